// Round 1
// baseline (157.233 us; speedup 1.0000x reference)
//
#include <hip/hip_runtime.h>
#include <cstdint>
#include <cstddef>

#define U   32
#define DM  2560
#define DI  5120
#define DS  16
#define RNK 160
#define XD  192   // RNK + 2*DS

// ---------------------------------------------------------------------------
// K1: dual skinny GEMM  xs = xb @ w_in_ssm, res = xb @ w_in_mlp
// grid (10, 16, 2), block 256.  K-chunk = 160, N-tile = 512 (2 cols/thread).
// Writes K-split partials (no atomics) to ws: part[z][kc][u][n]
// ---------------------------------------------------------------------------
__global__ __launch_bounds__(256) void k1_dualgemm(
    const float* __restrict__ x,
    const float* __restrict__ w_ssm,
    const float* __restrict__ w_mlp,
    float* __restrict__ part)
{
  __shared__ float xbs[U][160];
  const int nt = blockIdx.x, kc = blockIdx.y, z = blockIdx.z;
  const float* W = z ? w_mlp : w_ssm;
  float* po = part + (size_t)z * 16 * U * DI;
  const int k0 = kc * 160;

  for (int i = threadIdx.x; i < U * 160; i += 256) {
    int u = i / 160, k = i - u * 160;
    xbs[u][k] = x[u * DM + k0 + k];
  }
  __syncthreads();

  const int n0 = nt * 512 + threadIdx.x * 2;
  const float* Wp = W + (size_t)k0 * DI + n0;

  float a0[U], a1[U];
#pragma unroll
  for (int u = 0; u < U; ++u) { a0[u] = 0.f; a1[u] = 0.f; }

  for (int k = 0; k < 160; k += 4) {
    float2 w0 = *(const float2*)(Wp + (size_t)(k + 0) * DI);
    float2 w1 = *(const float2*)(Wp + (size_t)(k + 1) * DI);
    float2 w2 = *(const float2*)(Wp + (size_t)(k + 2) * DI);
    float2 w3 = *(const float2*)(Wp + (size_t)(k + 3) * DI);
#pragma unroll
    for (int u = 0; u < U; ++u) {
      float4 xv = *(const float4*)&xbs[u][k];   // wave-uniform -> LDS broadcast
      a0[u] = fmaf(xv.x, w0.x, a0[u]); a1[u] = fmaf(xv.x, w0.y, a1[u]);
      a0[u] = fmaf(xv.y, w1.x, a0[u]); a1[u] = fmaf(xv.y, w1.y, a1[u]);
      a0[u] = fmaf(xv.z, w2.x, a0[u]); a1[u] = fmaf(xv.z, w2.y, a1[u]);
      a0[u] = fmaf(xv.w, w3.x, a0[u]); a1[u] = fmaf(xv.w, w3.y, a1[u]);
    }
  }

#pragma unroll
  for (int u = 0; u < U; ++u) {
    *(float2*)(po + ((size_t)kc * U + u) * DI + n0) = make_float2(a0[u], a1[u]);
  }
}

// ---------------------------------------------------------------------------
// K2a: reduce K-split partials + conv + silu.  grid 640, block 256.
// c[u][d] = silu(cs1*w0 + cs2*w1 + cs3*w2 + xs*w3 + b);  res[u][d] = sum parts
// ---------------------------------------------------------------------------
__global__ __launch_bounds__(256) void k2a_convsilu(
    const float* __restrict__ part,
    const float* __restrict__ cs1, const float* __restrict__ cs2,
    const float* __restrict__ cs3,
    const float* __restrict__ cw,  const float* __restrict__ cb,
    float* __restrict__ c_ws, float* __restrict__ res_ws)
{
  const int i = blockIdx.x * 256 + threadIdx.x;   // [0, U*DI)
  float xs = 0.f, rs = 0.f;
#pragma unroll
  for (int p = 0; p < 16; ++p) {
    xs += part[(size_t)p * U * DI + i];
    rs += part[(size_t)(16 + p) * U * DI + i];
  }
  const int d = i % DI;
  float cc = cs1[i] * cw[d] + cs2[i] * cw[DI + d] + cs3[i] * cw[2 * DI + d]
           + xs * cw[3 * DI + d] + cb[d];
  cc = cc / (1.f + expf(-cc));                    // silu
  c_ws[i] = cc;
  res_ws[i] = rs;
}

// ---------------------------------------------------------------------------
// K2b: x_dbl = c @ x_proj_w  (32x5120 @ 5120x192), K-split atomics.
// grid 160 (k-chunks of 32), block 192 (one thread per output column).
// ---------------------------------------------------------------------------
__global__ __launch_bounds__(192) void k2b_xproj(
    const float* __restrict__ c_ws,
    const float* __restrict__ xpw,
    float* __restrict__ x_dbl)
{
  __shared__ float cl[U][32];
  const int k0 = blockIdx.x * 32;
  for (int i = threadIdx.x; i < U * 32; i += 192) {
    int u = i >> 5, kk = i & 31;
    cl[u][kk] = c_ws[u * DI + k0 + kk];
  }
  __syncthreads();

  const int n = threadIdx.x;   // 0..191
  float acc[U];
#pragma unroll
  for (int u = 0; u < U; ++u) acc[u] = 0.f;

  for (int kk = 0; kk < 32; kk += 4) {
    float w0 = xpw[(size_t)(k0 + kk + 0) * XD + n];
    float w1 = xpw[(size_t)(k0 + kk + 1) * XD + n];
    float w2 = xpw[(size_t)(k0 + kk + 2) * XD + n];
    float w3 = xpw[(size_t)(k0 + kk + 3) * XD + n];
#pragma unroll
    for (int u = 0; u < U; ++u) {
      float4 cv = *(const float4*)&cl[u][kk];
      acc[u] = fmaf(cv.x, w0, acc[u]);
      acc[u] = fmaf(cv.y, w1, acc[u]);
      acc[u] = fmaf(cv.z, w2, acc[u]);
      acc[u] = fmaf(cv.w, w3, acc[u]);
    }
  }
#pragma unroll
  for (int u = 0; u < U; ++u) atomicAdd(&x_dbl[u * XD + n], acc[u]);
}

// ---------------------------------------------------------------------------
// K3: dt GEMM + softplus + SSM update + y = einsum + D*c, then yr = y*res.
// grid (20, 4), block 256: thread = one d column, 8 users per block.y.
// ---------------------------------------------------------------------------
__global__ __launch_bounds__(256) void k3_ssm(
    const float* __restrict__ x_dbl,
    const float* __restrict__ dpw, const float* __restrict__ dpb,
    const float* __restrict__ alog, const float* __restrict__ Dp,
    const float* __restrict__ ssm,
    const float* __restrict__ c_ws, const float* __restrict__ res_ws,
    float* __restrict__ yr)
{
  __shared__ float xd[8][XD];
  const int d  = blockIdx.x * 256 + threadIdx.x;
  const int ug = blockIdx.y;            // users ug*8 .. ug*8+7

  for (int i = threadIdx.x; i < 8 * XD; i += 256) {
    int uu = i / XD, r = i - uu * XD;
    xd[uu][r] = x_dbl[(ug * 8 + uu) * XD + r];
  }
  __syncthreads();

  // dt pre-activation: x_dbl[:, :160] @ dt_proj_w
  float acc[8];
#pragma unroll
  for (int uu = 0; uu < 8; ++uu) acc[uu] = 0.f;
  const float* wp = dpw + d;
  for (int r = 0; r < RNK; r += 4) {
    float w0 = wp[(size_t)(r + 0) * DI];
    float w1 = wp[(size_t)(r + 1) * DI];
    float w2 = wp[(size_t)(r + 2) * DI];
    float w3 = wp[(size_t)(r + 3) * DI];
#pragma unroll
    for (int uu = 0; uu < 8; ++uu) {
      float4 xv = *(const float4*)&xd[uu][r];
      acc[uu] = fmaf(xv.x, w0, acc[uu]);
      acc[uu] = fmaf(xv.y, w1, acc[uu]);
      acc[uu] = fmaf(xv.z, w2, acc[uu]);
      acc[uu] = fmaf(xv.w, w3, acc[uu]);
    }
  }

  const float bias = dpb[d];
  const float Dv   = Dp[d];

  float As[DS];
#pragma unroll
  for (int s4 = 0; s4 < 4; ++s4) {
    float4 al = *(const float4*)&alog[d * DS + s4 * 4];
    As[s4 * 4 + 0] = -expf(al.x);
    As[s4 * 4 + 1] = -expf(al.y);
    As[s4 * 4 + 2] = -expf(al.z);
    As[s4 * 4 + 3] = -expf(al.w);
  }

#pragma unroll
  for (int uu = 0; uu < 8; ++uu) {
    const int u = ug * 8 + uu;
    float pre = acc[uu] + bias;
    float dt  = fmaxf(pre, 0.f) + log1pf(expf(-fabsf(pre)));  // softplus
    float cv  = c_ws[u * DI + d];
    float rv  = res_ws[u * DI + d];
    float dtc = dt * cv;
    const float* st = ssm + ((size_t)u * DI + d) * DS;
    float y = 0.f;
#pragma unroll
    for (int s4 = 0; s4 < 4; ++s4) {
      float4 sv = *(const float4*)&st[s4 * 4];
      const int s = s4 * 4;
      y += (sv.x * expf(dt * As[s + 0]) + dtc * xd[uu][RNK + s + 0]) * xd[uu][RNK + DS + s + 0];
      y += (sv.y * expf(dt * As[s + 1]) + dtc * xd[uu][RNK + s + 1]) * xd[uu][RNK + DS + s + 1];
      y += (sv.z * expf(dt * As[s + 2]) + dtc * xd[uu][RNK + s + 2]) * xd[uu][RNK + DS + s + 2];
      y += (sv.w * expf(dt * As[s + 3]) + dtc * xd[uu][RNK + s + 3]) * xd[uu][RNK + DS + s + 3];
    }
    y = fmaf(Dv, cv, y);
    yr[u * DI + d] = y * rv;
  }
}

// ---------------------------------------------------------------------------
// K4: out = (y*res) @ w_out  (32x5120 @ 5120x2560).  K-split atomics.
// grid (5, 64), block 256.  K-chunk = 80, N-tile = 512 (2 cols/thread).
// ---------------------------------------------------------------------------
__global__ __launch_bounds__(256) void k4_outgemm(
    const float* __restrict__ yr,
    const float* __restrict__ wout,
    float* __restrict__ out)
{
  __shared__ float yl[U][80];
  const int nt = blockIdx.x, kc = blockIdx.y;
  const int k0 = kc * 80;

  for (int i = threadIdx.x; i < U * 80; i += 256) {
    int u = i / 80, k = i - u * 80;
    yl[u][k] = yr[u * DI + k0 + k];
  }
  __syncthreads();

  const int n0 = nt * 512 + threadIdx.x * 2;
  const float* Wp = wout + (size_t)k0 * DM + n0;

  float a0[U], a1[U];
#pragma unroll
  for (int u = 0; u < U; ++u) { a0[u] = 0.f; a1[u] = 0.f; }

  for (int k = 0; k < 80; k += 4) {
    float2 w0 = *(const float2*)(Wp + (size_t)(k + 0) * DM);
    float2 w1 = *(const float2*)(Wp + (size_t)(k + 1) * DM);
    float2 w2 = *(const float2*)(Wp + (size_t)(k + 2) * DM);
    float2 w3 = *(const float2*)(Wp + (size_t)(k + 3) * DM);
#pragma unroll
    for (int u = 0; u < U; ++u) {
      float4 yv = *(const float4*)&yl[u][k];
      a0[u] = fmaf(yv.x, w0.x, a0[u]); a1[u] = fmaf(yv.x, w0.y, a1[u]);
      a0[u] = fmaf(yv.y, w1.x, a0[u]); a1[u] = fmaf(yv.y, w1.y, a1[u]);
      a0[u] = fmaf(yv.z, w2.x, a0[u]); a1[u] = fmaf(yv.z, w2.y, a1[u]);
      a0[u] = fmaf(yv.w, w3.x, a0[u]); a1[u] = fmaf(yv.w, w3.y, a1[u]);
    }
  }

#pragma unroll
  for (int u = 0; u < U; ++u) {
    atomicAdd(&out[u * DM + n0 + 0], a0[u]);
    atomicAdd(&out[u * DM + n0 + 1], a1[u]);
  }
}

// ---------------------------------------------------------------------------
extern "C" void kernel_launch(void* const* d_in, const int* in_sizes, int n_in,
                              void* d_out, int out_size, void* d_ws, size_t ws_size,
                              hipStream_t stream)
{
  const float* x    = (const float*)d_in[0];
  const float* wssm = (const float*)d_in[1];
  const float* wmlp = (const float*)d_in[2];
  const float* wout = (const float*)d_in[3];
  const float* cw   = (const float*)d_in[4];
  const float* cb   = (const float*)d_in[5];
  const float* cs1  = (const float*)d_in[6];
  const float* cs2  = (const float*)d_in[7];
  const float* cs3  = (const float*)d_in[8];
  const float* xpw  = (const float*)d_in[9];
  const float* dpw  = (const float*)d_in[10];
  const float* dpb  = (const float*)d_in[11];
  const float* alog = (const float*)d_in[12];
  const float* Dp   = (const float*)d_in[13];
  const float* ssm  = (const float*)d_in[14];
  float* out = (float*)d_out;
  float* ws  = (float*)d_ws;

  float* part   = ws;                      // 2*16*32*5120 = 5,242,880 floats
  float* c_ws   = part + (size_t)2 * 16 * U * DI;
  float* res_ws = c_ws + (size_t)U * DI;
  float* x_dbl  = res_ws + (size_t)U * DI;
  float* yrb    = x_dbl + (size_t)U * XD;

  hipMemsetAsync(x_dbl, 0, (size_t)U * XD * sizeof(float), stream);
  hipMemsetAsync(out,   0, (size_t)out_size * sizeof(float), stream);

  k1_dualgemm<<<dim3(10, 16, 2), 256, 0, stream>>>(x, wssm, wmlp, part);
  k2a_convsilu<<<640, 256, 0, stream>>>(part, cs1, cs2, cs3, cw, cb, c_ws, res_ws);
  k2b_xproj<<<160, 192, 0, stream>>>(c_ws, xpw, x_dbl);
  k3_ssm<<<dim3(20, 4), 256, 0, stream>>>(x_dbl, dpw, dpb, alog, Dp, ssm, c_ws, res_ws, yrb);
  k4_outgemm<<<dim3(5, 64), 256, 0, stream>>>(yrb, wout, out);
}